// Round 10
// baseline (521.935 us; speedup 1.0000x reference)
//
#include <hip/hip_runtime.h>

// MinkowskiUnion: out[map_out[i]] += feat[map_in[i]] for two input tensors.
// Three-phase inversion, v3 (hybrid of proven-best pieces):
//   1) k_fill_list: old = atomicExch(&head32[r], i) (4B exch, 6 MB region);
//      entries[i] = {link=old : v} coalesced.                     [~50 us]
//   2) k_compact: walk chain, write rec[r] = {s0..s3} coalesced; fan-in > 4
//      extras appended to ovf list via atomicAdd (~25K entries).  [~30 us]
//   3) k_gather_rec4: 16 lanes/row, plain 16B rec load, 4 INDEPENDENT feat
//      loads, NO chain logic, one NT store per row.               [~227 us]
//   4) k_overflow: rare extras via unsafeAtomicAdd.               [~8 us]
// Fallbacks: CSR counting-sort, then atomic scatter.

#define ROW_C 64
#define TBIT (1 << 30)
#define NIL  0xFFFFFFFFu
#define OVF_CAP (1 << 20)
#define SCAN_T 256
#define SCAN_PER 16
#define SCAN_CHUNK (SCAN_T * SCAN_PER)

typedef float f32x4 __attribute__((ext_vector_type(4)));
typedef int   i32x4 __attribute__((ext_vector_type(4)));
typedef unsigned long long u64;

__device__ __forceinline__ f32x4 feat_load(const float* __restrict__ feat1,
                                           const float* __restrict__ feat2,
                                           int v, int sub) {
    const float* f = (v & TBIT) ? feat2 : feat1;
    int ir = v & (TBIT - 1);
    return *reinterpret_cast<const f32x4*>(f + (size_t)ir * ROW_C + sub);
}

// ---------- phase 1: linked-list fill (u32 head) ----------
__global__ __launch_bounds__(256) void k_fill_list(
        const int* __restrict__ m1i, const int* __restrict__ m1o,
        const int* __restrict__ m2i, const int* __restrict__ m2o,
        int n1, int n2,
        unsigned* __restrict__ head, u64* __restrict__ entries) {
    int i = blockIdx.x * blockDim.x + threadIdx.x;
    int r, v;
    if (i < n1) { r = m1o[i]; v = m1i[i]; }
    else {
        int j = i - n1;
        if (j >= n2) return;
        r = m2o[j]; v = m2i[j] | TBIT;
    }
    unsigned old = atomicExch(&head[r], (unsigned)i);   // 4B exch, 6 MB region
    entries[i] = ((u64)old << 32) | (unsigned)v;        // coalesced store
}

// ---------- phase 2: chains -> 16B slot records + overflow list ----------
__global__ __launch_bounds__(256) void k_compact(
        const unsigned* __restrict__ head, const u64* __restrict__ entries,
        int* __restrict__ rec, int M,
        int* __restrict__ ovf, int* __restrict__ ovf_n) {
    int r = blockIdx.x * blockDim.x + threadIdx.x;
    if (r >= M) return;
    unsigned idx = head[r];                 // coalesced 4B
    int s0 = -1, s1 = -1, s2 = -1, s3 = -1;
    if (idx != NIL) {
        u64 e = entries[idx];
        s0 = (int)(unsigned)e; idx = (unsigned)(e >> 32);
        if (idx != NIL) {
            e = entries[idx];
            s1 = (int)(unsigned)e; idx = (unsigned)(e >> 32);
            if (idx != NIL) {
                e = entries[idx];
                s2 = (int)(unsigned)e; idx = (unsigned)(e >> 32);
                if (idx != NIL) {
                    e = entries[idx];
                    s3 = (int)(unsigned)e; idx = (unsigned)(e >> 32);
                    // rare fan-in > 4: push extras to overflow list
                    while (idx != NIL) {
                        e = entries[idx];
                        int p = atomicAdd(ovf_n, 1);
                        if (p < OVF_CAP) {
                            ovf[2 * p]     = r;
                            ovf[2 * p + 1] = (int)(unsigned)e;
                        }
                        idx = (unsigned)(e >> 32);
                    }
                }
            }
        }
    }
    i32x4 q = { s0, s1, s2, s3 };
    *reinterpret_cast<i32x4*>(rec + ((size_t)r << 2)) = q;  // coalesced
}

// ---------- phase 3: direct gather (no chain logic) ----------
__global__ __launch_bounds__(256) void k_gather_rec4(
        const float* __restrict__ feat1, const float* __restrict__ feat2,
        const int* __restrict__ rec, float* __restrict__ out, int M) {
    int gid = blockIdx.x * blockDim.x + threadIdx.x;
    int row = gid >> 4;                 // 16 threads per output row
    if (row >= M) return;
    int sub = (gid & 15) << 2;

    const i32x4 s = *reinterpret_cast<const i32x4*>(rec + ((size_t)row << 2));

    f32x4 acc = {0.f, 0.f, 0.f, 0.f};
    if (s.x != -1) acc += feat_load(feat1, feat2, s.x, sub);
    if (s.y != -1) acc += feat_load(feat1, feat2, s.y, sub);
    if (s.z != -1) acc += feat_load(feat1, feat2, s.z, sub);
    if (s.w != -1) acc += feat_load(feat1, feat2, s.w, sub);

    __builtin_nontemporal_store(acc,
        reinterpret_cast<f32x4*>(out + (size_t)row * ROW_C + sub));
}

// ---------- phase 4: rare overflow contributions ----------
__global__ void k_overflow(const int* __restrict__ ovf_n, const int* __restrict__ ovf,
                           const float* __restrict__ feat1, const float* __restrict__ feat2,
                           float* __restrict__ out) {
    int total = *ovf_n;
    if (total > OVF_CAP) total = OVF_CAP;
    int stride = gridDim.x * blockDim.x;
    for (int idx = blockIdx.x * blockDim.x + threadIdx.x; idx < total * 16; idx += stride) {
        int e = idx >> 4;
        int sub = (idx & 15) << 2;
        int r = ovf[2 * e];
        int v = ovf[2 * e + 1];
        f32x4 x = feat_load(feat1, feat2, v, sub);
        float* o = out + (size_t)r * ROW_C + sub;
        unsafeAtomicAdd(o + 0, x.x);
        unsafeAtomicAdd(o + 1, x.y);
        unsafeAtomicAdd(o + 2, x.z);
        unsafeAtomicAdd(o + 3, x.w);
    }
}

// ---------- CSR fallback ----------
__global__ void k_hist(const int* __restrict__ map_out, int n, int* __restrict__ counts) {
    int i = blockIdx.x * blockDim.x + threadIdx.x;
    if (i < n) atomicAdd(&counts[map_out[i]], 1);
}

__global__ void k_partial(const int* __restrict__ counts, int M, int* __restrict__ bsum) {
    __shared__ int lds[SCAN_T];
    int base = blockIdx.x * SCAN_CHUNK + threadIdx.x * SCAN_PER;
    int s = 0;
#pragma unroll
    for (int k = 0; k < SCAN_PER; k++) { int i = base + k; if (i < M) s += counts[i]; }
    lds[threadIdx.x] = s; __syncthreads();
    for (int off = SCAN_T / 2; off > 0; off >>= 1) {
        if (threadIdx.x < off) lds[threadIdx.x] += lds[threadIdx.x + off];
        __syncthreads();
    }
    if (threadIdx.x == 0) bsum[blockIdx.x] = lds[0];
}

__global__ void k_scan_bsum(int* __restrict__ bsum, int nblk) {
    __shared__ int lds[512];
    int t = threadIdx.x;
    lds[t] = (t < nblk) ? bsum[t] : 0;
    __syncthreads();
    for (int off = 1; off < 512; off <<= 1) {
        int v = (t >= off) ? lds[t - off] : 0;
        __syncthreads();
        lds[t] += v;
        __syncthreads();
    }
    if (t < nblk) bsum[t] = (t == 0) ? 0 : lds[t - 1];
}

__global__ void k_offsets(const int* __restrict__ counts, int M,
                          const int* __restrict__ bsum, int* __restrict__ cursor) {
    __shared__ int lds[SCAN_T];
    int base = blockIdx.x * SCAN_CHUNK + threadIdx.x * SCAN_PER;
    int c[SCAN_PER]; int s = 0;
#pragma unroll
    for (int k = 0; k < SCAN_PER; k++) { int i = base + k; c[k] = (i < M) ? counts[i] : 0; s += c[k]; }
    lds[threadIdx.x] = s; __syncthreads();
    for (int off = 1; off < SCAN_T; off <<= 1) {
        int v = (threadIdx.x >= off) ? lds[threadIdx.x - off] : 0;
        __syncthreads();
        lds[threadIdx.x] += v;
        __syncthreads();
    }
    int prefix = bsum[blockIdx.x] + ((threadIdx.x == 0) ? 0 : lds[threadIdx.x - 1]);
#pragma unroll
    for (int k = 0; k < SCAN_PER; k++) { int i = base + k; if (i < M) cursor[i] = prefix; prefix += c[k]; }
}

__global__ void k_fill(const int* __restrict__ map_in, const int* __restrict__ map_out,
                       int n, int tbit, int* __restrict__ cursor, int* __restrict__ csr) {
    int i = blockIdx.x * blockDim.x + threadIdx.x;
    if (i >= n) return;
    int r = map_out[i];
    int pos = atomicAdd(&cursor[r], 1);
    csr[pos] = map_in[i] | tbit;
}

__global__ void k_gather(const float* __restrict__ feat1, const float* __restrict__ feat2,
                         const int* __restrict__ counts, const int* __restrict__ cursor,
                         const int* __restrict__ csr, float* __restrict__ out, int M) {
    int gid = blockIdx.x * blockDim.x + threadIdx.x;
    int row = gid >> 4;
    if (row >= M) return;
    int sub = (gid & 15) << 2;

    int cnt = counts[row];
    int end = cursor[row];
    int start = end - cnt;

    float4 acc = {0.f, 0.f, 0.f, 0.f};
    for (int k = 0; k < cnt; k++) {
        int e = csr[start + k];
        const float* f = (e & TBIT) ? feat2 : feat1;
        int in_r = e & (TBIT - 1);
        float4 v = *reinterpret_cast<const float4*>(f + (size_t)in_r * ROW_C + sub);
        acc.x += v.x; acc.y += v.y; acc.z += v.z; acc.w += v.w;
    }
    *reinterpret_cast<float4*>(out + (size_t)row * ROW_C + sub) = acc;
}

// ---------- last-resort atomic scatter ----------
__global__ void scatter_add_rows(const float* __restrict__ feat,
                                 const int* __restrict__ map_in,
                                 const int* __restrict__ map_out,
                                 float* __restrict__ out,
                                 int n_rows) {
    int gid = blockIdx.x * blockDim.x + threadIdx.x;
    int row = gid >> 4;
    if (row >= n_rows) return;
    int sub = (gid & 15) << 2;
    int in_r  = map_in[row];
    int out_r = map_out[row];
    const float4 v = *reinterpret_cast<const float4*>(feat + (size_t)in_r * ROW_C + sub);
    float* o = out + (size_t)out_r * ROW_C + sub;
    unsafeAtomicAdd(o + 0, v.x);
    unsafeAtomicAdd(o + 1, v.y);
    unsafeAtomicAdd(o + 2, v.z);
    unsafeAtomicAdd(o + 3, v.w);
}

extern "C" void kernel_launch(void* const* d_in, const int* in_sizes, int n_in,
                              void* d_out, int out_size, void* d_ws, size_t ws_size,
                              hipStream_t stream) {
    const float* feat1    = (const float*)d_in[0];
    const float* feat2    = (const float*)d_in[1];
    const int*   map1_in  = (const int*)d_in[2];
    const int*   map1_out = (const int*)d_in[3];
    const int*   map2_in  = (const int*)d_in[4];
    const int*   map2_out = (const int*)d_in[5];
    float* out = (float*)d_out;

    const int n1 = in_sizes[2];
    const int n2 = in_sizes[4];
    const int M  = out_size / ROW_C;
    const int ntot = n1 + n2;
    const int block = 256;

    // ---- list + compact + rec path ----
    // layout: hdr(64B) | head[M] u32 (8B-align) | entries[ntot] u64 | rec[4M] | ovf[2*OVF_CAP]
    const size_t head_bytes = (((size_t)M * 4 + 7) & ~(size_t)7);
    const size_t need_list = 64 + head_bytes + (size_t)ntot * sizeof(u64)
                           + (size_t)M * 4 * sizeof(int)
                           + 2 * (size_t)OVF_CAP * sizeof(int);
    if (ws_size >= need_list) {
        int*      hdr     = (int*)d_ws;
        unsigned* head    = (unsigned*)((char*)d_ws + 64);
        u64*      entries = (u64*)((char*)d_ws + 64 + head_bytes);
        int*      rec     = (int*)(entries + ntot);
        int*      ovf     = rec + (size_t)M * 4;

        (void)hipMemsetAsync(hdr, 0, 64, stream);
        (void)hipMemsetAsync(head, 0xFF, (size_t)M * sizeof(unsigned), stream);  // NIL

        int gridf = (ntot + block - 1) / block;
        k_fill_list<<<gridf, block, 0, stream>>>(map1_in, map1_out, map2_in, map2_out,
                                                 n1, n2, head, entries);

        int gridc = (M + block - 1) / block;
        k_compact<<<gridc, block, 0, stream>>>(head, entries, rec, M, ovf, hdr);

        int gridg = (int)(((long long)M * 16 + block - 1) / block);
        k_gather_rec4<<<gridg, block, 0, stream>>>(feat1, feat2, rec, out, M);

        k_overflow<<<512, block, 0, stream>>>(hdr, ovf, feat1, feat2, out);
        return;
    }

    // ---- CSR fallback ----
    const int nblk = (M + SCAN_CHUNK - 1) / SCAN_CHUNK;
    const size_t need_csr = (size_t)(2 * (size_t)M + (size_t)ntot + (size_t)nblk) * sizeof(int);
    if (ws_size >= need_csr && nblk <= 512) {
        int* counts = (int*)d_ws;
        int* cursor = counts + M;
        int* csr    = cursor + M;
        int* bsum   = csr + ntot;

        (void)hipMemsetAsync(counts, 0, (size_t)M * sizeof(int), stream);
        k_hist<<<(n1 + block - 1) / block, block, 0, stream>>>(map1_out, n1, counts);
        k_hist<<<(n2 + block - 1) / block, block, 0, stream>>>(map2_out, n2, counts);
        k_partial<<<nblk, SCAN_T, 0, stream>>>(counts, M, bsum);
        k_scan_bsum<<<1, 512, 0, stream>>>(bsum, nblk);
        k_offsets<<<nblk, SCAN_T, 0, stream>>>(counts, M, bsum, cursor);
        k_fill<<<(n1 + block - 1) / block, block, 0, stream>>>(map1_in, map1_out, n1, 0, cursor, csr);
        k_fill<<<(n2 + block - 1) / block, block, 0, stream>>>(map2_in, map2_out, n2, TBIT, cursor, csr);
        int gridg = (int)(((long long)M * 16 + block - 1) / block);
        k_gather<<<gridg, block, 0, stream>>>(feat1, feat2, counts, cursor, csr, out, M);
        return;
    }

    // ---- atomic scatter ----
    (void)hipMemsetAsync(out, 0, (size_t)out_size * sizeof(float), stream);
    int grid1 = (int)(((long long)n1 * 16 + block - 1) / block);
    int grid2 = (int)(((long long)n2 * 16 + block - 1) / block);
    scatter_add_rows<<<grid1, block, 0, stream>>>(feat1, map1_in, map1_out, out, n1);
    scatter_add_rows<<<grid2, block, 0, stream>>>(feat2, map2_in, map2_out, out, n2);
}

// Round 11
// 330.077 us; speedup vs baseline: 1.5812x; 1.5812x over previous
//
#include <hip/hip_runtime.h>

// MinkowskiUnion: out[map_out[i]] += feat[map_in[i]] for two input tensors.
// Three-phase inversion (round-9 structure — measured best, 330 us):
//   1) k_fill_list: old = atomicExch(&head32[r], i)  (4B exch on 6 MB region);
//      entries[i] = {link=old : v} written coalesced.
//   2) k_compact: walk chain, write rec[r] = {s0,s1,s2,s3} coalesced.
//      Fan-in > 4 (~0.9% rows): s3 = 0x80000000 | entry_idx continuation.
//   3) k_gather_rec4: 16 lanes/row, NT-load rec (16B), up to 4 INDEPENDENT
//      feat row loads, one NT store per row. No f32 atomics anywhere.
// Round-10's overflow-list variant (separate k_overflow + atomicAdd counter)
// regressed 330 -> 522 us; reverted.
// Fallbacks: CSR counting-sort, then atomic scatter.

#define ROW_C 64
#define TBIT (1 << 30)
#define CONT 0x80000000u
#define NIL  0xFFFFFFFFu
#define SCAN_T 256
#define SCAN_PER 16
#define SCAN_CHUNK (SCAN_T * SCAN_PER)

typedef float f32x4 __attribute__((ext_vector_type(4)));
typedef int   i32x4 __attribute__((ext_vector_type(4)));
typedef unsigned long long u64;

__device__ __forceinline__ f32x4 feat_load(const float* __restrict__ feat1,
                                           const float* __restrict__ feat2,
                                           int v, int sub) {
    const float* f = (v & TBIT) ? feat2 : feat1;
    int ir = v & (TBIT - 1);
    return *reinterpret_cast<const f32x4*>(f + (size_t)ir * ROW_C + sub);
}

// ---------- phase 1: linked-list fill (u32 head) ----------
__global__ __launch_bounds__(256) void k_fill_list(
        const int* __restrict__ m1i, const int* __restrict__ m1o,
        const int* __restrict__ m2i, const int* __restrict__ m2o,
        int n1, int n2,
        unsigned* __restrict__ head, u64* __restrict__ entries) {
    int i = blockIdx.x * blockDim.x + threadIdx.x;
    int r, v;
    if (i < n1) { r = m1o[i]; v = m1i[i]; }
    else {
        int j = i - n1;
        if (j >= n2) return;
        r = m2o[j]; v = m2i[j] | TBIT;
    }
    unsigned old = atomicExch(&head[r], (unsigned)i);   // 4B exch, 6 MB region
    entries[i] = ((u64)old << 32) | (unsigned)v;        // coalesced store
}

// ---------- phase 2: chains -> 16B slot records ----------
__global__ __launch_bounds__(256) void k_compact(
        const unsigned* __restrict__ head, const u64* __restrict__ entries,
        int* __restrict__ rec, int M) {
    int r = blockIdx.x * blockDim.x + threadIdx.x;
    if (r >= M) return;
    unsigned idx = head[r];                 // coalesced 4B
    int s0 = -1, s1 = -1, s2 = -1, s3 = -1;
    if (idx != NIL) {
        u64 e = entries[idx];
        s0 = (int)(unsigned)e; idx = (unsigned)(e >> 32);
        if (idx != NIL) {
            e = entries[idx];
            s1 = (int)(unsigned)e; idx = (unsigned)(e >> 32);
            if (idx != NIL) {
                e = entries[idx];
                s2 = (int)(unsigned)e; idx = (unsigned)(e >> 32);
                if (idx != NIL) {
                    unsigned nx = idx;          // entry holding source #4
                    e = entries[idx];
                    unsigned link = (unsigned)(e >> 32);
                    if (link == NIL) {
                        s3 = (int)(unsigned)e;              // exactly 4
                    } else {
                        s3 = (int)(CONT | nx);              // >4: resume at #4
                    }
                }
            }
        }
    }
    i32x4 q = { s0, s1, s2, s3 };
    *reinterpret_cast<i32x4*>(rec + ((size_t)r << 2)) = q;  // coalesced
}

// ---------- phase 3: direct gather ----------
__global__ __launch_bounds__(256) void k_gather_rec4(
        const float* __restrict__ feat1, const float* __restrict__ feat2,
        const int* __restrict__ rec, const u64* __restrict__ entries,
        float* __restrict__ out, int M) {
    int gid = blockIdx.x * blockDim.x + threadIdx.x;
    int row = gid >> 4;                 // 16 threads per output row
    if (row >= M) return;
    int sub = (gid & 15) << 2;

    const i32x4 s = __builtin_nontemporal_load(
        reinterpret_cast<const i32x4*>(rec + ((size_t)row << 2)));

    f32x4 acc = {0.f, 0.f, 0.f, 0.f};
    if (s.x != -1) acc += feat_load(feat1, feat2, s.x, sub);
    if (s.y != -1) acc += feat_load(feat1, feat2, s.y, sub);
    if (s.z != -1) acc += feat_load(feat1, feat2, s.z, sub);
    if (s.w != -1) {
        if ((unsigned)s.w & CONT) {
            unsigned idx = (unsigned)s.w & 0x7FFFFFFFu;   // rare (~0.9% rows)
            while (idx != NIL) {
                u64 e = entries[idx];
                acc += feat_load(feat1, feat2, (int)(unsigned)e, sub);
                idx = (unsigned)(e >> 32);
            }
        } else {
            acc += feat_load(feat1, feat2, s.w, sub);
        }
    }

    __builtin_nontemporal_store(acc,
        reinterpret_cast<f32x4*>(out + (size_t)row * ROW_C + sub));
}

// ---------- CSR fallback ----------
__global__ void k_hist(const int* __restrict__ map_out, int n, int* __restrict__ counts) {
    int i = blockIdx.x * blockDim.x + threadIdx.x;
    if (i < n) atomicAdd(&counts[map_out[i]], 1);
}

__global__ void k_partial(const int* __restrict__ counts, int M, int* __restrict__ bsum) {
    __shared__ int lds[SCAN_T];
    int base = blockIdx.x * SCAN_CHUNK + threadIdx.x * SCAN_PER;
    int s = 0;
#pragma unroll
    for (int k = 0; k < SCAN_PER; k++) { int i = base + k; if (i < M) s += counts[i]; }
    lds[threadIdx.x] = s; __syncthreads();
    for (int off = SCAN_T / 2; off > 0; off >>= 1) {
        if (threadIdx.x < off) lds[threadIdx.x] += lds[threadIdx.x + off];
        __syncthreads();
    }
    if (threadIdx.x == 0) bsum[blockIdx.x] = lds[0];
}

__global__ void k_scan_bsum(int* __restrict__ bsum, int nblk) {
    __shared__ int lds[512];
    int t = threadIdx.x;
    lds[t] = (t < nblk) ? bsum[t] : 0;
    __syncthreads();
    for (int off = 1; off < 512; off <<= 1) {
        int v = (t >= off) ? lds[t - off] : 0;
        __syncthreads();
        lds[t] += v;
        __syncthreads();
    }
    if (t < nblk) bsum[t] = (t == 0) ? 0 : lds[t - 1];
}

__global__ void k_offsets(const int* __restrict__ counts, int M,
                          const int* __restrict__ bsum, int* __restrict__ cursor) {
    __shared__ int lds[SCAN_T];
    int base = blockIdx.x * SCAN_CHUNK + threadIdx.x * SCAN_PER;
    int c[SCAN_PER]; int s = 0;
#pragma unroll
    for (int k = 0; k < SCAN_PER; k++) { int i = base + k; c[k] = (i < M) ? counts[i] : 0; s += c[k]; }
    lds[threadIdx.x] = s; __syncthreads();
    for (int off = 1; off < SCAN_T; off <<= 1) {
        int v = (threadIdx.x >= off) ? lds[threadIdx.x - off] : 0;
        __syncthreads();
        lds[threadIdx.x] += v;
        __syncthreads();
    }
    int prefix = bsum[blockIdx.x] + ((threadIdx.x == 0) ? 0 : lds[threadIdx.x - 1]);
#pragma unroll
    for (int k = 0; k < SCAN_PER; k++) { int i = base + k; if (i < M) cursor[i] = prefix; prefix += c[k]; }
}

__global__ void k_fill(const int* __restrict__ map_in, const int* __restrict__ map_out,
                       int n, int tbit, int* __restrict__ cursor, int* __restrict__ csr) {
    int i = blockIdx.x * blockDim.x + threadIdx.x;
    if (i >= n) return;
    int r = map_out[i];
    int pos = atomicAdd(&cursor[r], 1);
    csr[pos] = map_in[i] | tbit;
}

__global__ void k_gather(const float* __restrict__ feat1, const float* __restrict__ feat2,
                         const int* __restrict__ counts, const int* __restrict__ cursor,
                         const int* __restrict__ csr, float* __restrict__ out, int M) {
    int gid = blockIdx.x * blockDim.x + threadIdx.x;
    int row = gid >> 4;
    if (row >= M) return;
    int sub = (gid & 15) << 2;

    int cnt = counts[row];
    int end = cursor[row];
    int start = end - cnt;

    float4 acc = {0.f, 0.f, 0.f, 0.f};
    for (int k = 0; k < cnt; k++) {
        int e = csr[start + k];
        const float* f = (e & TBIT) ? feat2 : feat1;
        int in_r = e & (TBIT - 1);
        float4 v = *reinterpret_cast<const float4*>(f + (size_t)in_r * ROW_C + sub);
        acc.x += v.x; acc.y += v.y; acc.z += v.z; acc.w += v.w;
    }
    *reinterpret_cast<float4*>(out + (size_t)row * ROW_C + sub) = acc;
}

// ---------- last-resort atomic scatter ----------
__global__ void scatter_add_rows(const float* __restrict__ feat,
                                 const int* __restrict__ map_in,
                                 const int* __restrict__ map_out,
                                 float* __restrict__ out,
                                 int n_rows) {
    int gid = blockIdx.x * blockDim.x + threadIdx.x;
    int row = gid >> 4;
    if (row >= n_rows) return;
    int sub = (gid & 15) << 2;
    int in_r  = map_in[row];
    int out_r = map_out[row];
    const float4 v = *reinterpret_cast<const float4*>(feat + (size_t)in_r * ROW_C + sub);
    float* o = out + (size_t)out_r * ROW_C + sub;
    unsafeAtomicAdd(o + 0, v.x);
    unsafeAtomicAdd(o + 1, v.y);
    unsafeAtomicAdd(o + 2, v.z);
    unsafeAtomicAdd(o + 3, v.w);
}

extern "C" void kernel_launch(void* const* d_in, const int* in_sizes, int n_in,
                              void* d_out, int out_size, void* d_ws, size_t ws_size,
                              hipStream_t stream) {
    const float* feat1    = (const float*)d_in[0];
    const float* feat2    = (const float*)d_in[1];
    const int*   map1_in  = (const int*)d_in[2];
    const int*   map1_out = (const int*)d_in[3];
    const int*   map2_in  = (const int*)d_in[4];
    const int*   map2_out = (const int*)d_in[5];
    float* out = (float*)d_out;

    const int n1 = in_sizes[2];
    const int n2 = in_sizes[4];
    const int M  = out_size / ROW_C;
    const int ntot = n1 + n2;
    const int block = 256;

    // ---- list + compact + rec path ----
    // layout: head[M] u32 (8B-aligned total) | entries[ntot] u64 | rec[4M] int
    const size_t head_bytes = (((size_t)M * 4 + 7) & ~(size_t)7);
    const size_t need_list = head_bytes + (size_t)ntot * sizeof(u64)
                           + (size_t)M * 4 * sizeof(int);
    if (ws_size >= need_list) {
        unsigned* head = (unsigned*)d_ws;
        u64* entries   = (u64*)((char*)d_ws + head_bytes);
        int* rec       = (int*)(entries + ntot);

        (void)hipMemsetAsync(head, 0xFF, (size_t)M * sizeof(unsigned), stream);  // NIL

        int gridf = (ntot + block - 1) / block;
        k_fill_list<<<gridf, block, 0, stream>>>(map1_in, map1_out, map2_in, map2_out,
                                                 n1, n2, head, entries);

        int gridc = (M + block - 1) / block;
        k_compact<<<gridc, block, 0, stream>>>(head, entries, rec, M);

        int gridg = (int)(((long long)M * 16 + block - 1) / block);
        k_gather_rec4<<<gridg, block, 0, stream>>>(feat1, feat2, rec, entries, out, M);
        return;
    }

    // ---- CSR fallback ----
    const int nblk = (M + SCAN_CHUNK - 1) / SCAN_CHUNK;
    const size_t need_csr = (size_t)(2 * (size_t)M + (size_t)ntot + (size_t)nblk) * sizeof(int);
    if (ws_size >= need_csr && nblk <= 512) {
        int* counts = (int*)d_ws;
        int* cursor = counts + M;
        int* csr    = cursor + M;
        int* bsum   = csr + ntot;

        (void)hipMemsetAsync(counts, 0, (size_t)M * sizeof(int), stream);
        k_hist<<<(n1 + block - 1) / block, block, 0, stream>>>(map1_out, n1, counts);
        k_hist<<<(n2 + block - 1) / block, block, 0, stream>>>(map2_out, n2, counts);
        k_partial<<<nblk, SCAN_T, 0, stream>>>(counts, M, bsum);
        k_scan_bsum<<<1, 512, 0, stream>>>(bsum, nblk);
        k_offsets<<<nblk, SCAN_T, 0, stream>>>(counts, M, bsum, cursor);
        k_fill<<<(n1 + block - 1) / block, block, 0, stream>>>(map1_in, map1_out, n1, 0, cursor, csr);
        k_fill<<<(n2 + block - 1) / block, block, 0, stream>>>(map2_in, map2_out, n2, TBIT, cursor, csr);
        int gridg = (int)(((long long)M * 16 + block - 1) / block);
        k_gather<<<gridg, block, 0, stream>>>(feat1, feat2, counts, cursor, csr, out, M);
        return;
    }

    // ---- atomic scatter ----
    (void)hipMemsetAsync(out, 0, (size_t)out_size * sizeof(float), stream);
    int grid1 = (int)(((long long)n1 * 16 + block - 1) / block);
    int grid2 = (int)(((long long)n2 * 16 + block - 1) / block);
    scatter_add_rows<<<grid1, block, 0, stream>>>(feat1, map1_in, map1_out, out, n1);
    scatter_add_rows<<<grid2, block, 0, stream>>>(feat2, map2_in, map2_out, out, n2);
}